// Round 4
// baseline (909.321 us; speedup 1.0000x reference)
//
#include <hip/hip_runtime.h>

#define BLOCK 256
#define GRID  2048
#define NBUCK 256
#define PIPT  16
#define PCHUNK (BLOCK * PIPT)

typedef int   v4i __attribute__((ext_vector_type(4)));
typedef float v4f __attribute__((ext_vector_type(4)));

__device__ __forceinline__ void block_reduce_out(float pos_acc, float neg_acc,
                                                 const float* alpha, float* out) {
    const float a = alpha[0];
    float v = pos_acc * ((1.0f - a) * 0.5f) + neg_acc * (a * 0.5f);
    #pragma unroll
    for (int off = 32; off > 0; off >>= 1)
        v += __shfl_down(v, off, 64);
    __shared__ float sdata[BLOCK / 64];
    const int lane = threadIdx.x & 63;
    const int wave = threadIdx.x >> 6;
    if (lane == 0) sdata[wave] = v;
    __syncthreads();
    if (threadIdx.x == 0) {
        float s = 0.0f;
        #pragma unroll
        for (int w = 0; w < BLOCK / 64; ++w) s += sdata[w];
        if (s != 0.0f) atomicAdd(out, s);
    }
}

// ======================= dense-count scheme =======================
// Pass 1: scatter nibble-packed multiplicities (pos: low nibble, neg: high
// nibble, 1 byte per matrix element) into a 67 MB count array.
// Max per-element per-class count is ~6 for this input (Poisson lambda<=0.12);
// nibble overflow probability ~5e-21 -> safe.
__global__ __launch_bounds__(BLOCK) void count_scatter_kernel(
    const int* __restrict__ px, const int* __restrict__ py, int npos,
    const int* __restrict__ nx, const int* __restrict__ ny, int nneg,
    unsigned* __restrict__ cnt)
{
    const int tid    = blockIdx.x * BLOCK + threadIdx.x;
    const int stride = GRID * BLOCK;

    {   // positives: +1 in low nibble of byte (o&3)
        const int n4 = npos >> 2;
        const v4i* x4 = (const v4i*)px;
        const v4i* y4 = (const v4i*)py;
        for (int i = tid; i < n4; i += stride) {
            v4i xs = __builtin_nontemporal_load(&x4[i]);
            v4i ys = __builtin_nontemporal_load(&y4[i]);
            unsigned o0 = ((unsigned)xs.x << 13) + (unsigned)ys.x;
            unsigned o1 = ((unsigned)xs.y << 13) + (unsigned)ys.y;
            unsigned o2 = ((unsigned)xs.z << 13) + (unsigned)ys.z;
            unsigned o3 = ((unsigned)xs.w << 13) + (unsigned)ys.w;
            atomicAdd(&cnt[o0 >> 2], 1u << ((o0 & 3u) * 8u));
            atomicAdd(&cnt[o1 >> 2], 1u << ((o1 & 3u) * 8u));
            atomicAdd(&cnt[o2 >> 2], 1u << ((o2 & 3u) * 8u));
            atomicAdd(&cnt[o3 >> 2], 1u << ((o3 & 3u) * 8u));
        }
        for (int i = (n4 << 2) + tid; i < npos; i += stride) {
            unsigned o = ((unsigned)px[i] << 13) + (unsigned)py[i];
            atomicAdd(&cnt[o >> 2], 1u << ((o & 3u) * 8u));
        }
    }
    {   // negatives: +1 in high nibble (inc = 16)
        const int n4 = nneg >> 2;
        const v4i* x4 = (const v4i*)nx;
        const v4i* y4 = (const v4i*)ny;
        for (int i = tid; i < n4; i += stride) {
            v4i xs = __builtin_nontemporal_load(&x4[i]);
            v4i ys = __builtin_nontemporal_load(&y4[i]);
            unsigned o0 = ((unsigned)xs.x << 13) + (unsigned)ys.x;
            unsigned o1 = ((unsigned)xs.y << 13) + (unsigned)ys.y;
            unsigned o2 = ((unsigned)xs.z << 13) + (unsigned)ys.z;
            unsigned o3 = ((unsigned)xs.w << 13) + (unsigned)ys.w;
            atomicAdd(&cnt[o0 >> 2], 16u << ((o0 & 3u) * 8u));
            atomicAdd(&cnt[o1 >> 2], 16u << ((o1 & 3u) * 8u));
            atomicAdd(&cnt[o2 >> 2], 16u << ((o2 & 3u) * 8u));
            atomicAdd(&cnt[o3 >> 2], 16u << ((o3 & 3u) * 8u));
        }
        for (int i = (n4 << 2) + tid; i < nneg; i += stride) {
            unsigned o = ((unsigned)nx[i] << 13) + (unsigned)ny[i];
            atomicAdd(&cnt[o >> 2], 16u << ((o & 3u) * 8u));
        }
    }
}

// Pass 2: fully-coalesced streaming sweep of R, D, cnt.
__global__ __launch_bounds__(BLOCK) void dense_loss_kernel(
    const float* __restrict__ R, const float* __restrict__ D,
    const float* __restrict__ alpha, const unsigned* __restrict__ cnt,
    int nwords, float* __restrict__ out)
{
    const int tid    = blockIdx.x * BLOCK + threadIdx.x;
    const int stride = GRID * BLOCK;
    float pos_acc = 0.0f, neg_acc = 0.0f;

    const v4f* R4 = (const v4f*)R;
    const v4f* D4 = (const v4f*)D;
    for (int w = tid; w < nwords; w += stride) {
        const unsigned c = __builtin_nontemporal_load(&cnt[w]);
        if (c) {   // 55% of words are zero -> skip both float4 loads
            v4f r = __builtin_nontemporal_load(&R4[w]);
            v4f d = __builtin_nontemporal_load(&D4[w]);
            #pragma unroll
            for (int j = 0; j < 4; ++j) {
                const unsigned b = (c >> (j * 8)) & 0xFFu;
                const float df = r[j] - d[j];
                const float d2 = df * df;
                pos_acc += d2 * (float)(b & 0xFu);
                neg_acc += d2 * (float)(b >> 4);
            }
        }
    }
    block_reduce_out(pos_acc, neg_acc, alpha, out);
}

// ======================= fallback 1: two-pass bucket scheme (proven R3) =======================
__global__ __launch_bounds__(BLOCK) void partition_kernel(
    const int* __restrict__ px, const int* __restrict__ py, int npos,
    const int* __restrict__ nx, const int* __restrict__ ny, int nneg,
    unsigned* __restrict__ items, unsigned* __restrict__ gcnt, int cap,
    const float* __restrict__ R, const float* __restrict__ D,
    const float* __restrict__ alpha, float* __restrict__ out)
{
    __shared__ unsigned s_cnt[NBUCK];
    __shared__ unsigned s_base[NBUCK];
    __shared__ unsigned s_cur[NBUCK];

    const int tid   = threadIdx.x;
    const int total = npos + nneg;
    const int nchunks = (total + PCHUNK - 1) / PCHUNK;

    float pos_acc = 0.0f, neg_acc = 0.0f;

    for (int c = blockIdx.x; c < nchunks; c += gridDim.x) {
        const int run = c * PCHUNK + tid * PIPT;
        const int nval = min(PIPT, max(0, total - run));

        unsigned it[PIPT];
        if (nval == PIPT && run + PIPT <= npos) {
            const v4i* x4 = (const v4i*)(px + run);
            const v4i* y4 = (const v4i*)(py + run);
            #pragma unroll
            for (int q = 0; q < PIPT / 4; ++q) {
                v4i xs = x4[q], ys = y4[q];
                it[q*4+0] = ((unsigned)xs.x << 13) | (unsigned)ys.x;
                it[q*4+1] = ((unsigned)xs.y << 13) | (unsigned)ys.y;
                it[q*4+2] = ((unsigned)xs.z << 13) | (unsigned)ys.z;
                it[q*4+3] = ((unsigned)xs.w << 13) | (unsigned)ys.w;
            }
        } else if (nval == PIPT && run >= npos && (((run - npos) & 3) == 0)) {
            const int j = run - npos;
            const v4i* x4 = (const v4i*)(nx + j);
            const v4i* y4 = (const v4i*)(ny + j);
            #pragma unroll
            for (int q = 0; q < PIPT / 4; ++q) {
                v4i xs = x4[q], ys = y4[q];
                it[q*4+0] = (((unsigned)xs.x << 13) | (unsigned)ys.x) | (1u << 26);
                it[q*4+1] = (((unsigned)xs.y << 13) | (unsigned)ys.y) | (1u << 26);
                it[q*4+2] = (((unsigned)xs.z << 13) | (unsigned)ys.z) | (1u << 26);
                it[q*4+3] = (((unsigned)xs.w << 13) | (unsigned)ys.w) | (1u << 26);
            }
        } else {
            for (int k = 0; k < PIPT; ++k) {
                const int gi = run + k;
                if (k < nval) {
                    if (gi < npos) it[k] = ((unsigned)px[gi] << 13) | (unsigned)py[gi];
                    else {
                        const int j = gi - npos;
                        it[k] = (((unsigned)nx[j] << 13) | (unsigned)ny[j]) | (1u << 26);
                    }
                } else it[k] = 0;
            }
        }

        s_cnt[tid] = 0;
        __syncthreads();
        #pragma unroll
        for (int k = 0; k < PIPT; ++k)
            if (k < nval) atomicAdd(&s_cnt[(it[k] >> 18) & 0xFF], 1u);
        __syncthreads();

        const unsigned cntv = s_cnt[tid];
        if (cntv) s_base[tid] = atomicAdd(&gcnt[tid], cntv);
        s_cur[tid] = 0;
        __syncthreads();

        #pragma unroll
        for (int k = 0; k < PIPT; ++k) {
            if (k < nval) {
                const unsigned b = (it[k] >> 18) & 0xFF;
                const unsigned p = atomicAdd(&s_cur[b], 1u);
                const unsigned gpos = s_base[b] + p;
                if (gpos < (unsigned)cap) {
                    items[(size_t)b * cap + gpos] = it[k];
                } else {
                    const unsigned o = it[k] & 0x3FFFFFFu;
                    const float d = R[o] - D[o];
                    if (it[k] >> 26) neg_acc += d * d; else pos_acc += d * d;
                }
            }
        }
        __syncthreads();
    }

    block_reduce_out(pos_acc, neg_acc, alpha, out);
}

__global__ __launch_bounds__(BLOCK) void gather_kernel(
    const float* __restrict__ R, const float* __restrict__ D,
    const float* __restrict__ alpha,
    const unsigned* __restrict__ items, const unsigned* __restrict__ gcnt,
    int cap, float* __restrict__ out)
{
    const int xcd = blockIdx.x & 7;
    const int g   = blockIdx.x >> 3;
    const unsigned team_stride = (GRID / 8) * BLOCK;

    float pos_acc = 0.0f, neg_acc = 0.0f;

    for (int bi = 0; bi < NBUCK / 8; ++bi) {
        const int b = bi * 8 + xcd;
        const unsigned n = min(gcnt[b], (unsigned)cap);
        const unsigned* ib = items + (size_t)b * cap;
        for (unsigned i = (unsigned)g * BLOCK + threadIdx.x; i < n; i += team_stride) {
            const unsigned it = ib[i];
            const unsigned o = it & 0x3FFFFFFu;
            const float d = R[o] - D[o];
            if (it >> 26) neg_acc += d * d; else pos_acc += d * d;
        }
    }

    block_reduce_out(pos_acc, neg_acc, alpha, out);
}

// ======================= fallback 2: direct =======================
__global__ __launch_bounds__(BLOCK) void dti_direct_kernel(
    const float* __restrict__ R, const float* __restrict__ D,
    const float* __restrict__ alpha,
    const int* __restrict__ px, const int* __restrict__ py, int npos,
    const int* __restrict__ nx, const int* __restrict__ ny, int nneg,
    float* __restrict__ out)
{
    const int tid = blockIdx.x * BLOCK + threadIdx.x;
    const int stride = gridDim.x * BLOCK;
    float pos_acc = 0.0f, neg_acc = 0.0f;
    {
        const int n4 = npos >> 2;
        const v4i* px4 = (const v4i*)px;
        const v4i* py4 = (const v4i*)py;
        for (int i = tid; i < n4; i += stride) {
            v4i xs = px4[i], ys = py4[i];
            int o0 = (xs.x << 13) + ys.x, o1 = (xs.y << 13) + ys.y;
            int o2 = (xs.z << 13) + ys.z, o3 = (xs.w << 13) + ys.w;
            float d0 = R[o0]-D[o0], d1 = R[o1]-D[o1], d2 = R[o2]-D[o2], d3 = R[o3]-D[o3];
            pos_acc += d0*d0 + d1*d1 + d2*d2 + d3*d3;
        }
        for (int i = (n4 << 2) + tid; i < npos; i += stride) {
            int o = (px[i] << 13) + py[i];
            float d = R[o] - D[o];
            pos_acc += d * d;
        }
    }
    {
        const int n4 = nneg >> 2;
        const v4i* nx4 = (const v4i*)nx;
        const v4i* ny4 = (const v4i*)ny;
        for (int i = tid; i < n4; i += stride) {
            v4i xs = nx4[i], ys = ny4[i];
            int o0 = (xs.x << 13) + ys.x, o1 = (xs.y << 13) + ys.y;
            int o2 = (xs.z << 13) + ys.z, o3 = (xs.w << 13) + ys.w;
            float d0 = R[o0]-D[o0], d1 = R[o1]-D[o1], d2 = R[o2]-D[o2], d3 = R[o3]-D[o3];
            neg_acc += d0*d0 + d1*d1 + d2*d2 + d3*d3;
        }
        for (int i = (n4 << 2) + tid; i < nneg; i += stride) {
            int o = (nx[i] << 13) + ny[i];
            float d = R[o] - D[o];
            neg_acc += d * d;
        }
    }
    block_reduce_out(pos_acc, neg_acc, alpha, out);
}

extern "C" void kernel_launch(void* const* d_in, const int* in_sizes, int n_in,
                              void* d_out, int out_size, void* d_ws, size_t ws_size,
                              hipStream_t stream) {
    const float* R     = (const float*)d_in[0];
    const float* D     = (const float*)d_in[1];
    const float* alpha = (const float*)d_in[2];
    const int*   px    = (const int*)d_in[3];
    const int*   py    = (const int*)d_in[4];
    const int*   nx    = (const int*)d_in[5];
    const int*   ny    = (const int*)d_in[6];
    const int    npos  = in_sizes[3];
    const int    nneg  = in_sizes[5];
    const int    nelem = in_sizes[0];        // 8192*8192 matrix elements
    const int    total = npos + nneg;

    float* out = (float*)d_out;
    hipMemsetAsync(out, 0, sizeof(float), stream);   // d_out poisoned before launch

    const size_t need_dense = (size_t)nelem;         // 1 byte/element nibble counts

    if (d_ws != nullptr && ws_size >= need_dense) {
        unsigned* cnt = (unsigned*)d_ws;
        hipMemsetAsync(cnt, 0, need_dense, stream);
        count_scatter_kernel<<<GRID, BLOCK, 0, stream>>>(
            px, py, npos, nx, ny, nneg, cnt);
        dense_loss_kernel<<<GRID, BLOCK, 0, stream>>>(
            R, D, alpha, cnt, nelem >> 2, out);
        return;
    }

    // fallback 1: two-pass bucket scheme (measured 708 us end-to-end)
    const int cap = total / NBUCK + total / (NBUCK * 4) + 1024;
    const size_t need_bucket = (size_t)NBUCK * cap * sizeof(unsigned) + NBUCK * sizeof(unsigned);
    if (d_ws != nullptr && ws_size >= need_bucket) {
        unsigned* items = (unsigned*)d_ws;
        unsigned* gcnt  = items + (size_t)NBUCK * cap;
        hipMemsetAsync(gcnt, 0, NBUCK * sizeof(unsigned), stream);
        partition_kernel<<<GRID, BLOCK, 0, stream>>>(
            px, py, npos, nx, ny, nneg, items, gcnt, cap, R, D, alpha, out);
        gather_kernel<<<GRID, BLOCK, 0, stream>>>(
            R, D, alpha, items, gcnt, cap, out);
        return;
    }

    // fallback 2: direct gather
    dti_direct_kernel<<<GRID, BLOCK, 0, stream>>>(
        R, D, alpha, px, py, npos, nx, ny, nneg, out);
}

// Round 5
// 716.337 us; speedup vs baseline: 1.2694x; 1.2694x over previous
//
#include <hip/hip_runtime.h>

#define BLOCK 256
#define GRID  2048
#define NBUCK 256
#define PIPT  16
#define PCHUNK (BLOCK * PIPT)   // 4096 items per chunk

typedef int v4i __attribute__((ext_vector_type(4)));

__device__ __forceinline__ void block_reduce_out(float pos_acc, float neg_acc,
                                                 const float* alpha, float* out) {
    const float a = alpha[0];
    float v = pos_acc * ((1.0f - a) * 0.5f) + neg_acc * (a * 0.5f);
    #pragma unroll
    for (int off = 32; off > 0; off >>= 1)
        v += __shfl_down(v, off, 64);
    __shared__ float sdata[BLOCK / 64];
    const int lane = threadIdx.x & 63;
    const int wave = threadIdx.x >> 6;
    if (lane == 0) sdata[wave] = v;
    __syncthreads();
    if (threadIdx.x == 0) {
        float s = 0.0f;
        #pragma unroll
        for (int w = 0; w < BLOCK / 64; ++w) s += sdata[w];
        if (s != 0.0f) atomicAdd(out, s);
    }
}

// ---------------- pass 1: LDS counting-sort partition, coalesced drain ----------------
__global__ __launch_bounds__(BLOCK) void partition_kernel(
    const int* __restrict__ px, const int* __restrict__ py, int npos,
    const int* __restrict__ nx, const int* __restrict__ ny, int nneg,
    unsigned* __restrict__ items, unsigned* __restrict__ gcnt, int cap,
    const float* __restrict__ R, const float* __restrict__ D,
    const float* __restrict__ alpha, float* __restrict__ out)
{
    __shared__ unsigned s_cnt[NBUCK];     // per-chunk histogram
    __shared__ unsigned s_pos[NBUCK];     // staging scatter cursor (init = excl prefix)
    __shared__ unsigned s_gmo[NBUCK];     // global_base - excl_prefix
    __shared__ unsigned s_wsum[BLOCK/64]; // per-wave scan partials
    __shared__ unsigned s_items[PCHUNK];  // bucket-ordered staging (16 KB)

    const int tid   = threadIdx.x;
    const int total = npos + nneg;
    const int nchunks = (total + PCHUNK - 1) / PCHUNK;

    float pos_acc = 0.0f, neg_acc = 0.0f;   // overflow-direct path (normally empty)

    for (int c = blockIdx.x; c < nchunks; c += GRID) {
        const int run  = c * PCHUNK + tid * PIPT;   // 16 consecutive items per thread
        const int nval = min(PIPT, max(0, total - run));

        unsigned it[PIPT];
        if (nval == PIPT && run + PIPT <= npos) {
            const v4i* x4 = (const v4i*)(px + run);
            const v4i* y4 = (const v4i*)(py + run);
            #pragma unroll
            for (int q = 0; q < PIPT / 4; ++q) {
                v4i xs = __builtin_nontemporal_load(&x4[q]);
                v4i ys = __builtin_nontemporal_load(&y4[q]);
                it[q*4+0] = ((unsigned)xs.x << 13) | (unsigned)ys.x;
                it[q*4+1] = ((unsigned)xs.y << 13) | (unsigned)ys.y;
                it[q*4+2] = ((unsigned)xs.z << 13) | (unsigned)ys.z;
                it[q*4+3] = ((unsigned)xs.w << 13) | (unsigned)ys.w;
            }
        } else if (nval == PIPT && run >= npos && (((run - npos) & 3) == 0)) {
            const int j = run - npos;
            const v4i* x4 = (const v4i*)(nx + j);
            const v4i* y4 = (const v4i*)(ny + j);
            #pragma unroll
            for (int q = 0; q < PIPT / 4; ++q) {
                v4i xs = __builtin_nontemporal_load(&x4[q]);
                v4i ys = __builtin_nontemporal_load(&y4[q]);
                it[q*4+0] = (((unsigned)xs.x << 13) | (unsigned)ys.x) | (1u << 26);
                it[q*4+1] = (((unsigned)xs.y << 13) | (unsigned)ys.y) | (1u << 26);
                it[q*4+2] = (((unsigned)xs.z << 13) | (unsigned)ys.z) | (1u << 26);
                it[q*4+3] = (((unsigned)xs.w << 13) | (unsigned)ys.w) | (1u << 26);
            }
        } else {
            for (int k = 0; k < PIPT; ++k) {
                const int gi = run + k;
                if (k < nval) {
                    if (gi < npos) it[k] = ((unsigned)px[gi] << 13) | (unsigned)py[gi];
                    else {
                        const int j = gi - npos;
                        it[k] = (((unsigned)nx[j] << 13) | (unsigned)ny[j]) | (1u << 26);
                    }
                } else it[k] = 0;
            }
        }

        // histogram
        s_cnt[tid] = 0;
        __syncthreads();
        #pragma unroll
        for (int k = 0; k < PIPT; ++k)
            if (k < nval) atomicAdd(&s_cnt[(it[k] >> 18) & 0xFF], 1u);
        __syncthreads();

        // exclusive prefix scan over 256 counters (wave shuffle + wave partials)
        const unsigned v = s_cnt[tid];
        unsigned x = v;
        #pragma unroll
        for (int o = 1; o < 64; o <<= 1) {
            unsigned t = __shfl_up(x, o, 64);
            if ((tid & 63) >= o) x += t;
        }
        if ((tid & 63) == 63) s_wsum[tid >> 6] = x;
        __syncthreads();
        unsigned wpre = 0;
        #pragma unroll
        for (int w = 0; w < BLOCK / 64; ++w)
            if (w < (tid >> 6)) wpre += s_wsum[w];
        const unsigned excl = wpre + x - v;

        // one global reservation per non-empty bucket
        unsigned gb = 0;
        if (v) gb = atomicAdd(&gcnt[tid], v);
        s_pos[tid] = excl;
        s_gmo[tid] = gb - excl;   // unsigned wrap ok: gpos = gb + (slot - excl)
        __syncthreads();

        // scatter into bucket-ordered LDS staging
        #pragma unroll
        for (int k = 0; k < PIPT; ++k) {
            if (k < nval) {
                const unsigned b = (it[k] >> 18) & 0xFF;
                const unsigned slot = atomicAdd(&s_pos[b], 1u);
                s_items[slot] = it[k];
            }
        }
        __syncthreads();

        // coalesced drain: consecutive lanes -> consecutive slots -> same-bucket runs
        const unsigned chunk_total = (unsigned)min(total - c * PCHUNK, PCHUNK);
        #pragma unroll
        for (int k = 0; k < PIPT; ++k) {
            const unsigned slot = (unsigned)(k * BLOCK) + tid;
            if (slot < chunk_total) {
                const unsigned itm = s_items[slot];
                const unsigned b = (itm >> 18) & 0xFF;
                const unsigned gpos = s_gmo[b] + slot;
                if (gpos < (unsigned)cap) {
                    __builtin_nontemporal_store(itm, &items[(size_t)b * cap + gpos]);
                } else {
                    // capacity overflow: process directly (correctness guarantee)
                    const unsigned o = itm & 0x3FFFFFFu;
                    const float d = R[o] - D[o];
                    if (itm >> 26) neg_acc += d * d; else pos_acc += d * d;
                }
            }
        }
        __syncthreads();
    }

    block_reduce_out(pos_acc, neg_acc, alpha, out);
}

// ---------------- pass 2: XCD-affine in-phase bucket gather (unchanged, proven) ----------------
__global__ __launch_bounds__(BLOCK) void gather_kernel(
    const float* __restrict__ R, const float* __restrict__ D,
    const float* __restrict__ alpha,
    const unsigned* __restrict__ items, const unsigned* __restrict__ gcnt,
    int cap, float* __restrict__ out)
{
    const int xcd = blockIdx.x & 7;
    const int g   = blockIdx.x >> 3;
    const unsigned team_stride = (GRID / 8) * BLOCK;

    float pos_acc = 0.0f, neg_acc = 0.0f;

    for (int bi = 0; bi < NBUCK / 8; ++bi) {
        const int b = bi * 8 + xcd;
        const unsigned n = min(gcnt[b], (unsigned)cap);
        const unsigned* ib = items + (size_t)b * cap;
        for (unsigned i = (unsigned)g * BLOCK + threadIdx.x; i < n; i += team_stride) {
            const unsigned it = ib[i];
            const unsigned o = it & 0x3FFFFFFu;
            const float d = R[o] - D[o];
            if (it >> 26) neg_acc += d * d; else pos_acc += d * d;
        }
    }

    block_reduce_out(pos_acc, neg_acc, alpha, out);
}

// ---------------- fallback: direct gather ----------------
__global__ __launch_bounds__(BLOCK) void dti_direct_kernel(
    const float* __restrict__ R, const float* __restrict__ D,
    const float* __restrict__ alpha,
    const int* __restrict__ px, const int* __restrict__ py, int npos,
    const int* __restrict__ nx, const int* __restrict__ ny, int nneg,
    float* __restrict__ out)
{
    const int tid = blockIdx.x * BLOCK + threadIdx.x;
    const int stride = gridDim.x * BLOCK;
    float pos_acc = 0.0f, neg_acc = 0.0f;
    {
        const int n4 = npos >> 2;
        const v4i* px4 = (const v4i*)px;
        const v4i* py4 = (const v4i*)py;
        for (int i = tid; i < n4; i += stride) {
            v4i xs = px4[i], ys = py4[i];
            int o0 = (xs.x << 13) + ys.x, o1 = (xs.y << 13) + ys.y;
            int o2 = (xs.z << 13) + ys.z, o3 = (xs.w << 13) + ys.w;
            float d0 = R[o0]-D[o0], d1 = R[o1]-D[o1], d2 = R[o2]-D[o2], d3 = R[o3]-D[o3];
            pos_acc += d0*d0 + d1*d1 + d2*d2 + d3*d3;
        }
        for (int i = (n4 << 2) + tid; i < npos; i += stride) {
            int o = (px[i] << 13) + py[i];
            float d = R[o] - D[o];
            pos_acc += d * d;
        }
    }
    {
        const int n4 = nneg >> 2;
        const v4i* nx4 = (const v4i*)nx;
        const v4i* ny4 = (const v4i*)ny;
        for (int i = tid; i < n4; i += stride) {
            v4i xs = nx4[i], ys = ny4[i];
            int o0 = (xs.x << 13) + ys.x, o1 = (xs.y << 13) + ys.y;
            int o2 = (xs.z << 13) + ys.z, o3 = (xs.w << 13) + ys.w;
            float d0 = R[o0]-D[o0], d1 = R[o1]-D[o1], d2 = R[o2]-D[o2], d3 = R[o3]-D[o3];
            neg_acc += d0*d0 + d1*d1 + d2*d2 + d3*d3;
        }
        for (int i = (n4 << 2) + tid; i < nneg; i += stride) {
            int o = (nx[i] << 13) + ny[i];
            float d = R[o] - D[o];
            neg_acc += d * d;
        }
    }
    block_reduce_out(pos_acc, neg_acc, alpha, out);
}

extern "C" void kernel_launch(void* const* d_in, const int* in_sizes, int n_in,
                              void* d_out, int out_size, void* d_ws, size_t ws_size,
                              hipStream_t stream) {
    const float* R     = (const float*)d_in[0];
    const float* D     = (const float*)d_in[1];
    const float* alpha = (const float*)d_in[2];
    const int*   px    = (const int*)d_in[3];
    const int*   py    = (const int*)d_in[4];
    const int*   nx    = (const int*)d_in[5];
    const int*   ny    = (const int*)d_in[6];
    const int    npos  = in_sizes[3];
    const int    nneg  = in_sizes[5];
    const int    total = npos + nneg;

    float* out = (float*)d_out;
    hipMemsetAsync(out, 0, sizeof(float), stream);   // d_out poisoned before launch

    // bucket capacity: mean + 25% + 1024 (>>10 sigma for uniform draws), 4-aligned
    const int cap = ((total / NBUCK + total / (NBUCK * 4) + 1024 + 3) & ~3);
    const size_t need = (size_t)NBUCK * cap * sizeof(unsigned) + NBUCK * sizeof(unsigned);

    if (d_ws != nullptr && ws_size >= need) {
        unsigned* items = (unsigned*)d_ws;
        unsigned* gcnt  = items + (size_t)NBUCK * cap;
        hipMemsetAsync(gcnt, 0, NBUCK * sizeof(unsigned), stream);
        partition_kernel<<<GRID, BLOCK, 0, stream>>>(
            px, py, npos, nx, ny, nneg, items, gcnt, cap, R, D, alpha, out);
        gather_kernel<<<GRID, BLOCK, 0, stream>>>(
            R, D, alpha, items, gcnt, cap, out);
    } else {
        dti_direct_kernel<<<GRID, BLOCK, 0, stream>>>(
            R, D, alpha, px, py, npos, nx, ny, nneg, out);
    }
}